// Round 3
// baseline (669.171 us; speedup 1.0000x reference)
//
#include <hip/hip_runtime.h>
#include <math.h>

// GlobalAttentionPool: fused linear-score + segment softmax + weighted pool.
// Single pass over x (512 MB) using online softmax per segment.
// batch is sorted -> segments contiguous.
//
// Round-3 restructure vs round-2 (667 us):
//  - Each segment split into C=8 chunks -> 8192 partial-state blocks
//    (was 1024 = only 4 blocks/CU). Partial states merged by a tiny
//    second kernel (~4 MB extra traffic vs 512 MB stream).
//  - Tile-max online update: one alpha + 4 exps per 8-row tile instead of
//    8 serial exp-dependent chains; acc update is an independent FMA tree.

#define DIM 128
#define CHUNKS 8
#define NEG_HUGE (-3.0e38f)

// ---- Kernel 1: segment offset table from sorted batch -----------------
// off[s] = first index i with batch[i] >= s, for s in [0, B]; off[B] = N.
__global__ void seg_offsets_kernel(const int* __restrict__ batch,
                                   int* __restrict__ off, int N, int B) {
    int i = blockIdx.x * blockDim.x + threadIdx.x;
    if (i >= N) return;
    int bi = batch[i];
    int bp = (i == 0) ? -1 : batch[i - 1];
    for (int s = bp + 1; s <= bi; ++s) off[s] = i;
    if (i == N - 1) {
        for (int s = bi + 1; s <= B; ++s) off[s] = N;
    }
}

// ---- Kernel 2: partial online-softmax attention pool per chunk --------
__global__ __launch_bounds__(256) void gap_partial_kernel(
    const float* __restrict__ x,
    const int*   __restrict__ off,
    const float* __restrict__ W,
    const float* __restrict__ bias,
    float*       __restrict__ ws_acc,   // [B*CHUNKS][DIM]
    float*       __restrict__ ws_ml)    // [B*CHUNKS][2]
{
    const int seg   = blockIdx.x / CHUNKS;
    const int chunk = blockIdx.x % CHUNKS;
    const int tid   = threadIdx.x;
    const int wave  = tid >> 6;   // 0..3
    const int lane  = tid & 63;
    const int half  = lane >> 5;  // which row of the float4-load pair
    const int hl    = lane & 31;  // lane within 32-lane row group

    const int sstart = off[seg];
    const int send   = off[seg + 1];
    const int len    = send - sstart;
    const int cs     = sstart + (int)(((long long)len * chunk) / CHUNKS);
    const int ce     = sstart + (int)(((long long)len * (chunk + 1)) / CHUNKS);

    // Lane hl of each half holds W[4*hl .. 4*hl+3].
    const float4 wv = ((const float4*)W)[hl];
    const float  b0 = bias[0];

    // Online-softmax state per (wave, half): acc distributed over 32 lanes.
    float  m = NEG_HUGE;
    float  l = 0.0f;
    float4 acc = make_float4(0.f, 0.f, 0.f, 0.f);

    // Tile: 8 rows per wave-iteration (k=0..3, 2 rows per float4 load),
    // 32 rows per block-iteration.
    int p = cs + wave * 8;

    float4 xv[4];
    #pragma unroll
    for (int k = 0; k < 4; ++k) {
        int row = p + 2 * k + half;
        xv[k] = (row < ce) ? ((const float4*)(x + (size_t)row * DIM))[hl]
                           : make_float4(0.f, 0.f, 0.f, 0.f);
    }

    for (; p < ce; p += 32) {
        // Prefetch next tile while we reduce the current one.
        float4 xn[4];
        #pragma unroll
        for (int k = 0; k < 4; ++k) {
            int row = p + 32 + 2 * k + half;
            xn[k] = (row < ce) ? ((const float4*)(x + (size_t)row * DIM))[hl]
                               : make_float4(0.f, 0.f, 0.f, 0.f);
        }

        // Partial dots for 8 rows (4 per half-wave).
        float s[4];
        #pragma unroll
        for (int k = 0; k < 4; ++k)
            s[k] = xv[k].x * wv.x + xv[k].y * wv.y + xv[k].z * wv.z + xv[k].w * wv.w;

        // Batched butterfly within each 32-lane half.
        #pragma unroll
        for (int offd = 16; offd > 0; offd >>= 1) {
            #pragma unroll
            for (int k = 0; k < 4; ++k)
                s[k] += __shfl_xor(s[k], offd, 64);
        }

        // Tile-max online update: one alpha, 4 independent weights.
        bool valid[4];
        #pragma unroll
        for (int k = 0; k < 4; ++k) {
            valid[k] = (p + 2 * k + half) < ce;
            s[k] = valid[k] ? (s[k] + b0) : NEG_HUGE;
        }
        const float tile_m = fmaxf(fmaxf(s[0], s[1]), fmaxf(s[2], s[3]));
        const float m_new  = fmaxf(m, tile_m);
        const float alpha  = __expf(m - m_new);   // exp(0)=1 while both NEG_HUGE
        float w[4];
        #pragma unroll
        for (int k = 0; k < 4; ++k)
            w[k] = valid[k] ? __expf(s[k] - m_new) : 0.0f;

        l = l * alpha + ((w[0] + w[1]) + (w[2] + w[3]));
        acc.x = acc.x * alpha + ((w[0]*xv[0].x + w[1]*xv[1].x) + (w[2]*xv[2].x + w[3]*xv[3].x));
        acc.y = acc.y * alpha + ((w[0]*xv[0].y + w[1]*xv[1].y) + (w[2]*xv[2].y + w[3]*xv[3].y));
        acc.z = acc.z * alpha + ((w[0]*xv[0].z + w[1]*xv[1].z) + (w[2]*xv[2].z + w[3]*xv[3].z));
        acc.w = acc.w * alpha + ((w[0]*xv[0].w + w[1]*xv[1].w) + (w[2]*xv[2].w + w[3]*xv[3].w));
        m = m_new;

        #pragma unroll
        for (int k = 0; k < 4; ++k) xv[k] = xn[k];
    }

    // ---- Merge 8 per-(wave,half) states into one chunk state ----
    __shared__ float sm[8];
    __shared__ float sl[8];
    __shared__ float sacc[8][DIM];

    const int sid = wave * 2 + half;
    sacc[sid][4 * hl + 0] = acc.x;
    sacc[sid][4 * hl + 1] = acc.y;
    sacc[sid][4 * hl + 2] = acc.z;
    sacc[sid][4 * hl + 3] = acc.w;
    if (hl == 0) { sm[sid] = m; sl[sid] = l; }
    __syncthreads();

    if (tid < DIM) {
        float m_p = NEG_HUGE;
        #pragma unroll
        for (int h = 0; h < 8; ++h) m_p = fmaxf(m_p, sm[h]);
        float num = 0.0f, den = 0.0f;
        #pragma unroll
        for (int h = 0; h < 8; ++h) {
            float a = __expf(sm[h] - m_p);   // empty: exp(0)=1 but l=0,acc=0
            num += sacc[h][tid] * a;
            den += sl[h] * a;
        }
        ws_acc[(size_t)blockIdx.x * DIM + tid] = num;
        if (tid == 0) {
            ws_ml[(size_t)blockIdx.x * 2 + 0] = m_p;
            ws_ml[(size_t)blockIdx.x * 2 + 1] = den;
        }
    }
}

// ---- Kernel 3: merge chunk states -> output ---------------------------
__global__ __launch_bounds__(DIM) void gap_merge_kernel(
    const float* __restrict__ ws_acc,
    const float* __restrict__ ws_ml,
    float*       __restrict__ out)
{
    const int seg = blockIdx.x;
    const int t   = threadIdx.x;

    float mc[CHUNKS], lc[CHUNKS];
    float m_tot = NEG_HUGE;
    #pragma unroll
    for (int c = 0; c < CHUNKS; ++c) {
        mc[c] = ws_ml[(size_t)(seg * CHUNKS + c) * 2 + 0];
        lc[c] = ws_ml[(size_t)(seg * CHUNKS + c) * 2 + 1];
        m_tot = fmaxf(m_tot, mc[c]);
    }
    float num = 0.0f, den = 0.0f;
    #pragma unroll
    for (int c = 0; c < CHUNKS; ++c) {
        float a = __expf(mc[c] - m_tot);  // all-empty: exp(0)=1 with l=0
        num += ws_acc[(size_t)(seg * CHUNKS + c) * DIM + t] * a;
        den += lc[c] * a;
    }
    // Matches reference attn = ex / (seg_sum + 1e-16); empty segment -> 0.
    out[(size_t)seg * DIM + t] = num / (den + 1e-16f);
}

extern "C" void kernel_launch(void* const* d_in, const int* in_sizes, int n_in,
                              void* d_out, int out_size, void* d_ws, size_t ws_size,
                              hipStream_t stream) {
    const float* x     = (const float*)d_in[0];
    // d_in[1] = edge_index (unused by the forward math)
    const int*   batch = (const int*)d_in[2];
    const float* W     = (const float*)d_in[3];
    const float* bias  = (const float*)d_in[4];
    float*       out   = (float*)d_out;

    const int N = in_sizes[2];          // number of nodes
    const int B = out_size / DIM;       // number of segments

    // Workspace layout: acc [B*CHUNKS*DIM] f32 | ml [B*CHUNKS*2] f32 | off [B+1] i32
    float* ws_acc = (float*)d_ws;
    float* ws_ml  = ws_acc + (size_t)B * CHUNKS * DIM;
    int*   off    = (int*)(ws_ml + (size_t)B * CHUNKS * 2);

    seg_offsets_kernel<<<(N + 255) / 256, 256, 0, stream>>>(batch, off, N, B);
    gap_partial_kernel<<<B * CHUNKS, 256, 0, stream>>>(x, off, W, bias, ws_acc, ws_ml);
    gap_merge_kernel<<<B, DIM, 0, stream>>>(ws_acc, ws_ml, out);
}